// Round 1
// baseline (1038.277 us; speedup 1.0000x reference)
//
#include <hip/hip_runtime.h>
#include <hip/hip_bf16.h>
#include <stdint.h>

#define B_ 256
#define T_ 512
#define C_ 14
#define CO_ 32
#define H_ 128
#define G_ 512   // 4*H

// ---------------- Kernel 1: conv over time + Leaky spike -> 32-bit masks ----
__global__ __launch_bounds__(256) void k_conv_spike(
    const float* __restrict__ x, const float* __restrict__ cw,
    const float* __restrict__ cb, unsigned int* __restrict__ cur1) {
  __shared__ float w_s[CO_ * C_ * 3];  // 1344
  __shared__ float b_s[CO_];
  for (int i = threadIdx.x; i < CO_ * C_ * 3; i += blockDim.x) w_s[i] = cw[i];
  if (threadIdx.x < CO_) b_s[threadIdx.x] = cb[threadIdx.x];
  __syncthreads();
  int idx = blockIdx.x * blockDim.x + threadIdx.x;  // b*T + t
  if (idx >= B_ * T_) return;
  int b = idx / T_, t = idx % T_;
  float xin[3][C_];
#pragma unroll
  for (int k = 0; k < 3; ++k) {
    int tt = t + k - 1;
    if (tt < 0 || tt >= T_) {
#pragma unroll
      for (int c = 0; c < C_; ++c) xin[k][c] = 0.f;
    } else {
      const float* p = x + ((size_t)b * T_ + tt) * C_;
#pragma unroll
      for (int c = 0; c < C_; ++c) xin[k][c] = p[c];
    }
  }
  unsigned int bits = 0u;
  for (int oc = 0; oc < CO_; ++oc) {
    float s = b_s[oc];
    const float* wr = &w_s[oc * C_ * 3];
#pragma unroll
    for (int ic = 0; ic < C_; ++ic)
#pragma unroll
      for (int k = 0; k < 3; ++k) s = fmaf(xin[k][ic], wr[ic * 3 + k], s);
    if (s - 1.0f > 0.f) bits |= (1u << oc);
  }
  cur1[idx] = bits;
}

// ---------------- Kernel 2: SLSTM layer 1 (2 rows per block) ---------------
__global__ __launch_bounds__(512, 2) void k_slstm1(
    const unsigned int* __restrict__ cur1, const float* __restrict__ w_ih,
    const float* __restrict__ w_hh, const float* __restrict__ b_ih,
    const float* __restrict__ b_hh, const float* __restrict__ thr_p,
    unsigned long long* __restrict__ spk_bits, unsigned int* __restrict__ count) {
  const int g = threadIdx.x;       // gate 0..511
  const int t0 = blockIdx.x * 2;   // rows t0, t0+1
  const float thr = thr_p[0];

  float wih[32], whh[H_];
#pragma unroll
  for (int k = 0; k < 32; ++k) wih[k] = w_ih[g * 32 + k];
#pragma unroll
  for (int k = 0; k < H_; ++k) whh[k] = w_hh[g * H_ + k];
  const float bias = b_ih[g] + b_hh[g];

  __shared__ float mem_s[2][H_];
  __shared__ float gate_s[2][G_];
  float syn = 0.f;  // used by update threads (g<256): row = g>>7, h = g&127
  int cnt = 0;
  if (g < 256) mem_s[g >> 7][g & 127] = 0.f;
  __syncthreads();

  for (int b = 0; b < B_; ++b) {
    unsigned int bits0 = cur1[b * T_ + t0];
    unsigned int bits1 = cur1[b * T_ + t0 + 1];
    float s0 = bias, s1 = bias;
#pragma unroll
    for (int k = 0; k < 32; ++k) {
      s0 += ((bits0 >> k) & 1u) ? wih[k] : 0.f;
      s1 += ((bits1 >> k) & 1u) ? wih[k] : 0.f;
    }
#pragma unroll
    for (int k = 0; k < H_; ++k) {
      s0 = fmaf(whh[k], mem_s[0][k], s0);
      s1 = fmaf(whh[k], mem_s[1][k], s1);
    }
    gate_s[0][g] = s0;
    gate_s[1][g] = s1;
    __syncthreads();
    if (g < 256) {
      const int r = g >> 7, h = g & 127;
      float gi = gate_s[r][h];
      float gf = gate_s[r][h + 128];
      float gg = gate_s[r][h + 256];
      float go = gate_s[r][h + 384];
      float i = 1.f / (1.f + expf(-gi));
      float f = 1.f / (1.f + expf(-gf));
      float gt = tanhf(gg);
      float o = 1.f / (1.f + expf(-go));
      float memp = mem_s[r][h];
      float rst = (memp - thr > 0.f) ? thr : 0.f;  // reset * thr
      syn = f * syn + i * gt;
      float mm = o * tanhf(syn) - rst;
      mem_s[r][h] = mm;
      bool spk = (mm - thr) > 0.f;
      cnt += spk ? 1 : 0;
      unsigned long long m = __ballot(spk);
      if ((g & 63) == 0)
        spk_bits[((size_t)b * T_ + t0 + r) * 2 + ((h >> 6) & 1)] = m;
    }
    __syncthreads();
  }
  if (g < 256) atomicAdd(&count[g & 127], (unsigned int)cnt);
}

// ---------------- Kernel 3: BN params from spike counts --------------------
__global__ void k_bnprep(const unsigned int* __restrict__ count,
                         const float* __restrict__ gamma,
                         const float* __restrict__ beta,
                         float* __restrict__ a, float* __restrict__ c) {
  int h = threadIdx.x;
  if (h >= H_) return;
  const float inv_n = 1.f / (float)(B_ * T_);
  float mu = (float)count[h] * inv_n;
  float var = mu * (1.f - mu);
  float ai = gamma[h] / sqrtf(var + 1e-5f);
  a[h] = ai;
  c[h] = beta[h] - mu * ai;
}

// ---------------- Kernel 4: fold BN into layer-2 input weights -------------
__global__ void k_fold(const float* __restrict__ w_ih2,
                       const float* __restrict__ b_ih2,
                       const float* __restrict__ b_hh2,
                       const float* __restrict__ a, const float* __restrict__ c,
                       float* __restrict__ W2p, float* __restrict__ cg) {
  int gi = blockIdx.x * blockDim.x + threadIdx.x;  // 0..511
  if (gi >= G_) return;
  float s = b_ih2[gi] + b_hh2[gi];
  for (int h = 0; h < H_; ++h) {
    float w = w_ih2[gi * H_ + h];
    W2p[h * G_ + gi] = w * a[h];  // column-major: [h][512]
    s = fmaf(w, c[h], s);
  }
  cg[gi] = s;
}

// ---------------- Kernel 5: SLSTM layer 2 (+ mean-over-b accum) ------------
__global__ __launch_bounds__(512, 2) void k_slstm2(
    const unsigned long long* __restrict__ spk_bits,
    const float* __restrict__ w_hh, const float* __restrict__ W2p,
    const float* __restrict__ cg, const float* __restrict__ thr_p,
    float* __restrict__ acc_out) {
  const int g = threadIdx.x;
  const int t0 = blockIdx.x * 2;
  const float thr = thr_p[0];

  float whh[H_];
#pragma unroll
  for (int k = 0; k < H_; ++k) whh[k] = w_hh[g * H_ + k];
  const float bias = cg[g];

  __shared__ float mem_s[2][H_];
  __shared__ float gate_s[2][G_];
  float syn = 0.f, accv = 0.f;
  if (g < 256) mem_s[g >> 7][g & 127] = 0.f;
  __syncthreads();

  for (int b = 0; b < B_; ++b) {
    unsigned long long m00 = spk_bits[((size_t)b * T_ + t0) * 2 + 0];
    unsigned long long m01 = spk_bits[((size_t)b * T_ + t0) * 2 + 1];
    unsigned long long m10 = spk_bits[((size_t)b * T_ + t0 + 1) * 2 + 0];
    unsigned long long m11 = spk_bits[((size_t)b * T_ + t0 + 1) * 2 + 1];
    float s0 = bias, s1 = bias;
    // input term: only set bits contribute (wave-uniform masks)
    while (m00) { int h = __ffsll(m00) - 1; m00 &= m00 - 1; s0 += W2p[h * G_ + g]; }
    while (m01) { int h = __ffsll(m01) - 1; m01 &= m01 - 1; s0 += W2p[(h + 64) * G_ + g]; }
    while (m10) { int h = __ffsll(m10) - 1; m10 &= m10 - 1; s1 += W2p[h * G_ + g]; }
    while (m11) { int h = __ffsll(m11) - 1; m11 &= m11 - 1; s1 += W2p[(h + 64) * G_ + g]; }
#pragma unroll
    for (int k = 0; k < H_; ++k) {
      s0 = fmaf(whh[k], mem_s[0][k], s0);
      s1 = fmaf(whh[k], mem_s[1][k], s1);
    }
    gate_s[0][g] = s0;
    gate_s[1][g] = s1;
    __syncthreads();
    if (g < 256) {
      const int r = g >> 7, h = g & 127;
      float gi = gate_s[r][h];
      float gf = gate_s[r][h + 128];
      float gg = gate_s[r][h + 256];
      float go = gate_s[r][h + 384];
      float i = 1.f / (1.f + expf(-gi));
      float f = 1.f / (1.f + expf(-gf));
      float gt = tanhf(gg);
      float o = 1.f / (1.f + expf(-go));
      float memp = mem_s[r][h];
      float rst = (memp - thr > 0.f) ? thr : 0.f;
      syn = f * syn + i * gt;
      float mm = o * tanhf(syn) - rst;
      mem_s[r][h] = mm;
      accv += mm;
    }
    __syncthreads();
  }
  if (g < 256) acc_out[(size_t)(t0 + (g >> 7)) * H_ + (g & 127)] = accv;
}

// ---------------- Kernel 6: final mean + FC --------------------------------
__global__ void k_out(const float* __restrict__ accv,
                      const float* __restrict__ fc_w,
                      const float* __restrict__ fc_b, float* __restrict__ out) {
  int idx = blockIdx.x * blockDim.x + threadIdx.x;  // t*8+n
  if (idx >= T_ * 8) return;
  int t = idx >> 3, n = idx & 7;
  float s = fc_b[n];
  for (int h = 0; h < H_; ++h)
    s = fmaf(accv[t * H_ + h] * (1.f / 256.f), fc_w[n * H_ + h], s);
  out[idx] = s;
}

extern "C" void kernel_launch(void* const* d_in, const int* in_sizes, int n_in,
                              void* d_out, int out_size, void* d_ws, size_t ws_size,
                              hipStream_t stream) {
  const float* x       = (const float*)d_in[0];
  const float* conv_w  = (const float*)d_in[1];
  const float* conv_b  = (const float*)d_in[2];
  const float* w_ih1   = (const float*)d_in[3];
  const float* w_hh1   = (const float*)d_in[4];
  const float* b_ih1   = (const float*)d_in[5];
  const float* b_hh1   = (const float*)d_in[6];
  const float* thr1    = (const float*)d_in[7];
  const float* w_ih2   = (const float*)d_in[8];
  const float* w_hh2   = (const float*)d_in[9];
  const float* b_ih2   = (const float*)d_in[10];
  const float* b_hh2   = (const float*)d_in[11];
  const float* thr2    = (const float*)d_in[12];
  const float* bn_g    = (const float*)d_in[13];
  const float* bn_b    = (const float*)d_in[14];
  const float* fc_w    = (const float*)d_in[15];
  const float* fc_b    = (const float*)d_in[16];
  float* out = (float*)d_out;

  char* ws = (char*)d_ws;
  unsigned int* cur1       = (unsigned int*)(ws);                    // 512 KB
  unsigned long long* spk  = (unsigned long long*)(ws + (512 << 10));// 2 MB
  unsigned int* count      = (unsigned int*)(ws + (2560 << 10));     // 512 B
  float* a                 = (float*)(ws + (2561 << 10));            // 512 B
  float* c                 = (float*)(ws + (2562 << 10));            // 512 B
  float* cg                = (float*)(ws + (2563 << 10));            // 2 KB
  float* W2p               = (float*)(ws + (2566 << 10));            // 256 KB
  float* accv              = (float*)(ws + (2822 << 10));            // 256 KB

  hipMemsetAsync(count, 0, H_ * sizeof(unsigned int), stream);
  k_conv_spike<<<(B_ * T_ + 255) / 256, 256, 0, stream>>>(x, conv_w, conv_b, cur1);
  k_slstm1<<<T_ / 2, 512, 0, stream>>>(cur1, w_ih1, w_hh1, b_ih1, b_hh1, thr1,
                                       spk, count);
  k_bnprep<<<1, 128, 0, stream>>>(count, bn_g, bn_b, a, c);
  k_fold<<<1, 512, 0, stream>>>(w_ih2, b_ih2, b_hh2, a, c, W2p, cg);
  k_slstm2<<<T_ / 2, 512, 0, stream>>>(spk, w_hh2, W2p, cg, thr2, accv);
  k_out<<<(T_ * 8 + 255) / 256, 256, 0, stream>>>(accv, fc_w, fc_b, out);
}